// Round 1
// baseline (245.465 us; speedup 1.0000x reference)
//
#include <hip/hip_runtime.h>
#include <cstdint>
#include <cstddef>

#define N_COLS 4096
#define TPB 256
#define RPB 4                      // rows per block (software-pipelined)
#define NCOPY 8
#define CSTR 260                   // words per copy (copy-major layout); 16B-aligned, bank-rotating
#define NHWORDS (NCOPY * CSTR)     // 2080 words = 8320 B
#define SURV_CAP 64

static_assert(NHWORDS % 4 == 0, "hist must be uint4-clearable");

// --- kernel 1: boost factors, double-precision exp rounded to fp32 ---
__global__ void boost_kernel(const float* __restrict__ dc,
                             const int* __restrict__ kp,
                             float* __restrict__ bf) {
    int i = blockIdx.x * blockDim.x + threadIdx.x;
    if (i < N_COLS) {
        float td = (float)kp[0] / (float)N_COLS;   // float32(k)/float32(n), like ref
        float arg = td - dc[i];                    // fp32 subtract, like ref
        bf[i] = (float)exp((double)arg);           // ~correctly-rounded fp32 exp
    }
}

__device__ __forceinline__ uint32_t orderable(uint32_t u) {
    return (u & 0x80000000u) ? ~u : (u | 0x80000000u);  // float order == uint order
}

// LDS-only barrier: orders DS ops across the workgroup WITHOUT draining vmcnt,
// so prefetch global loads stay in flight across the selection phases.
__device__ __forceinline__ void bar_lgkm() {
    asm volatile("s_waitcnt lgkmcnt(0)\n\ts_barrier" ::: "memory");
}

// Process one row held in xv[]; optionally prefetch the next row into xn[].
template<bool PREF>
__device__ __forceinline__ void process_row(
    const float4* __restrict__ xpref, float4 (&xv)[4], float4 (&xn)[4],
    const float4 (&bfv)[4], float4* __restrict__ orow, uint32_t k,
    uint32_t* __restrict__ s_hist, uint32_t* __restrict__ s_cnt,
    uint32_t* __restrict__ s_cand, uint32_t* __restrict__ s_m2,
    int tid, int lane, uint32_t copy)
{
    // issue next-row loads FIRST; they ride out the whole selection below
    if constexpr (PREF) {
        #pragma unroll
        for (int j = 0; j < 4; ++j) xn[j] = xpref[tid + j * TPB];
    }

    // previous row's LDS readers must be done before we re-clear
    bar_lgkm();
    {
        uint4* h4 = (uint4*)s_hist;
        uint4 z; z.x = z.y = z.z = z.w = 0u;
        for (int w = tid; w < NHWORDS / 4; w += TPB) h4[w] = z;
    }
    if (tid == 0) *s_m2 = 0u;
    bar_lgkm();

    // boosted values for this row (bf cached in registers by caller)
    float xb[16];
    #pragma unroll
    for (int j = 0; j < 4; ++j) {
        xb[j * 4 + 0] = xv[j].x * bfv[j].x;
        xb[j * 4 + 1] = xv[j].y * bfv[j].y;
        xb[j * 4 + 2] = xv[j].z * bfv[j].z;
        xb[j * 4 + 3] = xv[j].w * bfv[j].w;
    }

    // single histogram pass over candidates >= T0 with the composite digit
    // d = min((bits>>16) - 0x3F80, 255): monotone for all floats >= 1.0.
    const float T0f = 1.10f;   // performance heuristic only; exactness guarded below
    #pragma unroll
    for (int e = 0; e < 16; ++e) {
        if (xb[e] >= T0f) {
            uint32_t d = (__float_as_uint(xb[e]) >> 16) - 0x3F80u;
            d = d > 255u ? 255u : d;
            atomicAdd(&s_hist[copy * CSTR + d], 1u);
        }
    }
    bar_lgkm();

    uint32_t rem = k;
    uint32_t dsel, packed;
    {
        // copy-major reduce: per-c uint4 reads are stride-16B -> conflict-free
        uint32_t vv0 = 0, vv1 = 0, vv2 = 0, vv3 = 0;
        #pragma unroll
        for (int c = 0; c < NCOPY; ++c) {
            uint4 a = *(const uint4*)&s_hist[c * CSTR + 4 * lane];
            vv0 += a.x; vv1 += a.y; vv2 += a.z; vv3 += a.w;
        }
        uint32_t s3 = vv3, s2 = vv2 + s3, s1 = vv1 + s2, s0 = vv0 + s1;
        uint32_t T = s0;
        #pragma unroll
        for (int off = 1; off < 64; off <<= 1) {
            uint32_t t = (uint32_t)__shfl_down((int)T, off, 64);
            if (lane + off < 64) T += t;
        }
        uint32_t Tex = T - s0;   // sum over lanes > lane
        uint32_t S0 = Tex + s0, S1 = Tex + s1, S2 = Tex + s2, S3 = Tex + s3;
        int b = -1; uint32_t sn = 0;
        if (S3 >= rem)      { b = 3; sn = S3 - vv3; }
        else if (S2 >= rem) { b = 2; sn = S2 - vv2; }
        else if (S1 >= rem) { b = 1; sn = S1 - vv1; }
        else if (S0 >= rem) { b = 0; sn = S0 - vv0; }
        packed = (b >= 0) ? ((((uint32_t)(4 * lane + b + 1)) << 16) | sn) : 0u;
        #pragma unroll
        for (int off = 1; off < 64; off <<= 1) {
            uint32_t o = (uint32_t)__shfl_xor((int)packed, off, 64);
            packed = packed > o ? packed : o;
        }
        dsel = (packed >> 16) - 1u;      // selected digit (if packed != 0)
        rem -= (packed & 0xFFFFu);       // rank within selected bin
    }

    float thr = 0.0f;
    bool need_fallback = (packed == 0u) || (dsel == 255u);

    if (!need_fallback) {
        const uint32_t hi16 = 0x3F80u + dsel;
        // scatter survivors (order irrelevant); may include a few elements in
        // [1.09375, T0) when dsel==0x0C — all strictly below every histogrammed
        // member, and rem <= member count, so the rem-th largest is unaffected.
        #pragma unroll
        for (int e = 0; e < 16; ++e) {
            uint32_t ub = __float_as_uint(xb[e]);
            if ((ub >> 16) == hi16) {
                uint32_t pos = atomicAdd(s_m2, 1u);
                if (pos < SURV_CAP) s_cand[pos] = ub;
            }
        }
        bar_lgkm();
        const uint32_t m2 = *s_m2;       // block-uniform broadcast read
        if (m2 <= SURV_CAP) {
            // replicated 16-bit ballot descent: every wave loads the same
            // survivors, so every wave's ballot counts are the global counts.
            uint32_t cv = ((uint32_t)lane < m2) ? s_cand[lane] : ((~hi16) << 16);
            uint32_t cur = 0;
            #pragma unroll
            for (int bpos = 15; bpos >= 0; --bpos) {
                uint32_t t  = (hi16 << 16) | cur | (1u << bpos);
                uint32_t mk = ~((1u << bpos) - 1u);
                uint32_t c  = (uint32_t)__popcll(__ballot(((cv ^ t) & mk) == 0u));
                if (c >= rem) cur |= (1u << bpos);
                else          rem -= c;
            }
            thr = __uint_as_float((hi16 << 16) | cur);
        } else {
            need_fallback = true;
        }
    }

    if (need_fallback) {
        // exact 4-pass orderable radix over all 4096 elements (any input)
        bar_lgkm();
        {
            uint4* h4 = (uint4*)s_hist;
            uint4 z; z.x = z.y = z.z = z.w = 0u;
            for (int w = tid; w < NHWORDS / 4; w += TPB) h4[w] = z;
        }
        bar_lgkm();
        uint32_t prefix = 0;
        rem = k;
        const uint32_t pmasks[4] = {0u, 0xFF000000u, 0xFFFF0000u, 0xFFFFFF00u};
        #pragma unroll 1
        for (int pass = 0; pass < 4; ++pass) {
            const int shift = 24 - pass * 8;
            const uint32_t pm = pmasks[pass];
            #pragma unroll
            for (int e = 0; e < 16; ++e) {
                uint32_t ou = orderable(__float_as_uint(xb[e]));
                if (((ou ^ prefix) & pm) == 0u)
                    atomicAdd(&s_hist[copy * CSTR + ((ou >> shift) & 255u)], 1u);
            }
            bar_lgkm();
            // reduce copies of bin `tid` (stride-4B lanes: conflict-free), zero for next pass
            {
                uint32_t sum = 0;
                #pragma unroll
                for (int c = 0; c < NCOPY; ++c) {
                    sum += s_hist[c * CSTR + tid];
                    s_hist[c * CSTR + tid] = 0u;
                }
                s_cnt[tid] = sum;
            }
            bar_lgkm();
            // replicated suffix-scan digit pick over s_cnt
            uint4 v = ((const uint4*)s_cnt)[lane];
            uint32_t s3 = v.w, s2 = v.z + s3, s1 = v.y + s2, s0 = v.x + s1;
            uint32_t T = s0;
            #pragma unroll
            for (int off = 1; off < 64; off <<= 1) {
                uint32_t t = (uint32_t)__shfl_down((int)T, off, 64);
                if (lane + off < 64) T += t;
            }
            uint32_t Tex = T - s0;
            uint32_t S0 = Tex + s0, S1 = Tex + s1, S2 = Tex + s2, S3 = Tex + s3;
            int b = -1; uint32_t sn = 0;
            if (S3 >= rem)      { b = 3; sn = S3 - v.w; }
            else if (S2 >= rem) { b = 2; sn = S2 - v.z; }
            else if (S1 >= rem) { b = 1; sn = S1 - v.y; }
            else if (S0 >= rem) { b = 0; sn = S0 - v.x; }
            uint32_t pk = (b >= 0) ? ((((uint32_t)(4 * lane + b + 1)) << 16) | sn) : 0u;
            #pragma unroll
            for (int off = 1; off < 64; off <<= 1) {
                uint32_t o = (uint32_t)__shfl_xor((int)pk, off, 64);
                pk = pk > o ? pk : o;
            }
            prefix |= ((pk >> 16) - 1u) << shift;
            rem -= (pk & 0xFFFFu);
        }
        // orderable-space -> float bits
        uint32_t tu = (prefix & 0x80000000u) ? (prefix & 0x7FFFFFFFu) : ~prefix;
        thr = __uint_as_float(tu);
    }

    // epilogue: mask from boosted (regs) vs thr, values from x (regs)
    #pragma unroll
    for (int j = 0; j < 4; ++j) {
        float4 o;
        o.x = (xb[j * 4 + 0] >= thr) ? xv[j].x : 0.0f;
        o.y = (xb[j * 4 + 1] >= thr) ? xv[j].y : 0.0f;
        o.z = (xb[j * 4 + 2] >= thr) ? xv[j].z : 0.0f;
        o.w = (xb[j * 4 + 3] >= thr) ? xv[j].w : 0.0f;
        orow[tid + j * TPB] = o;
    }
}

// RPB rows per block, register double-buffered: loads for row r+1 are issued
// before the selection of row r; all intra-row barriers are lgkm-only so the
// prefetch stays in flight across the whole selection.
__global__ __launch_bounds__(TPB) void kwinner_kernel(
    const float* __restrict__ x, const float* __restrict__ bf,
    const int* __restrict__ kp, float* __restrict__ out, int rows)
{
    __shared__ __align__(16) uint32_t s_hist[NHWORDS];  // copy-major: [copy*CSTR + bin]
    __shared__ uint32_t s_cnt[256];        // fallback only
    __shared__ uint32_t s_cand[SURV_CAP];
    __shared__ uint32_t s_m2;

    const int tid  = threadIdx.x;
    const int lane = tid & 63;
    const uint32_t copy = (uint32_t)(tid & (NCOPY - 1));
    const uint32_t k = (uint32_t)kp[0];

    size_t r0 = (size_t)blockIdx.x * RPB;
    size_t r1 = r0 + 1, r2 = r0 + 2, r3 = r0 + 3;
    const size_t rmax = (size_t)rows - 1;   // ragged tail: clamp -> benign same-value rewrite
    if (r0 > rmax) r0 = rmax;
    if (r1 > rmax) r1 = rmax;
    if (r2 > rmax) r2 = rmax;
    if (r3 > rmax) r3 = rmax;

    // boost factors cached in registers once per block (amortized over RPB rows)
    const float4* br = (const float4*)bf;
    float4 bfv[4];
    #pragma unroll
    for (int j = 0; j < 4; ++j) bfv[j] = br[tid + j * TPB];

    const size_t s4 = N_COLS / 4;
    const float4* xg = (const float4*)x;
    float4* og = (float4*)out;

    float4 xA[4], xB[4];
    #pragma unroll
    for (int j = 0; j < 4; ++j) xA[j] = xg[r0 * s4 + tid + j * TPB];

    process_row<true >(xg + r1 * s4, xA, xB, bfv, og + r0 * s4, k,
                       s_hist, s_cnt, s_cand, &s_m2, tid, lane, copy);
    process_row<true >(xg + r2 * s4, xB, xA, bfv, og + r1 * s4, k,
                       s_hist, s_cnt, s_cand, &s_m2, tid, lane, copy);
    process_row<true >(xg + r3 * s4, xA, xB, bfv, og + r2 * s4, k,
                       s_hist, s_cnt, s_cand, &s_m2, tid, lane, copy);
    process_row<false>(xg,           xB, xA, bfv, og + r3 * s4, k,
                       s_hist, s_cnt, s_cand, &s_m2, tid, lane, copy);
}

extern "C" void kernel_launch(void* const* d_in, const int* in_sizes, int n_in,
                              void* d_out, int out_size, void* d_ws, size_t ws_size,
                              hipStream_t stream) {
    const float* x  = (const float*)d_in[0];
    const float* dc = (const float*)d_in[1];
    const int*   kp = (const int*)d_in[2];
    float* out = (float*)d_out;
    float* bf  = (float*)d_ws;                 // 4096 floats of scratch

    const int n    = in_sizes[1];              // 4096
    const int rows = in_sizes[0] / n;          // 8192

    boost_kernel<<<(n + TPB - 1) / TPB, TPB, 0, stream>>>(dc, kp, bf);
    const int nb = (rows + RPB - 1) / RPB;     // 2048 blocks
    kwinner_kernel<<<nb, TPB, 0, stream>>>(x, bf, kp, out, rows);
}

// Round 2
// 242.902 us; speedup vs baseline: 1.0106x; 1.0106x over previous
//
#include <hip/hip_runtime.h>
#include <cstdint>
#include <cstddef>

#define N_COLS 4096
#define TPB 256
#define WPB 4                      // waves per block = rows per block (independent waves!)
#define HSTRW 260                  // words per histogram copy (bank-rotating copy stride)
#define SURV_CAP 64

// --- kernel 1: boost factors, double-precision exp rounded to fp32 ---
__global__ void boost_kernel(const float* __restrict__ dc,
                             const int* __restrict__ kp,
                             float* __restrict__ bf) {
    int i = blockIdx.x * blockDim.x + threadIdx.x;
    if (i < N_COLS) {
        float td = (float)kp[0] / (float)N_COLS;   // float32(k)/float32(n), like ref
        float arg = td - dc[i];                    // fp32 subtract, like ref
        bf[i] = (float)exp((double)arg);           // ~correctly-rounded fp32 exp
    }
}

__device__ __forceinline__ uint32_t orderable(uint32_t u) {
    return (u & 0x80000000u) ? ~u : (u | 0x80000000u);  // float order == uint order
}

// Wave-local LDS fence: each wave owns its histogram/survivor region, so
// ordering needs only lgkmcnt(0) within the wave — NO s_barrier anywhere
// in the selection. Waves run fully independently.
__device__ __forceinline__ void wave_lgkm() {
    asm volatile("s_waitcnt lgkmcnt(0)" ::: "memory");
}

// One wave per row. Row held entirely in registers (16 float4/lane).
// Boosted values are recomputed from x(regs) * bf(LDS) per phase to keep
// VGPRs <= 128 (4 waves/SIMD).
__global__ __launch_bounds__(TPB, 4) void kwinner_kernel(
    const float* __restrict__ x, const float* __restrict__ bf,
    const int* __restrict__ kp, float* __restrict__ out, int rows)
{
    __shared__ __align__(16) float    s_bf[N_COLS];            // 16 KB, read-only after stage
    __shared__ __align__(16) uint32_t s_hist[WPB][2][HSTRW];   // per-wave, 2 copies
    __shared__ uint32_t s_cand[WPB][SURV_CAP];                 // per-wave survivors
    __shared__ uint32_t s_m2[WPB * 8];                         // per-wave counter, bank-spread

    const int tid  = threadIdx.x;
    const int w    = tid >> 6;
    const int lane = tid & 63;

    // stage bf once per block (the ONLY __syncthreads in the kernel)
    {
        const float4* br = (const float4*)bf;
        float4* sb = (float4*)s_bf;
        #pragma unroll
        for (int j = 0; j < 4; ++j) sb[tid + j * TPB] = br[tid + j * TPB];
    }
    __syncthreads();

    size_t row = (size_t)blockIdx.x * WPB + (size_t)w;
    const size_t rmax = (size_t)rows - 1;     // ragged tail: clamp -> benign duplicate write
    if (row > rmax) row = rmax;

    const float4* xr   = (const float4*)(x + row * (size_t)N_COLS);
    float4*       orow = (float4*)(out + row * (size_t)N_COLS);
    const float4* bf4  = (const float4*)s_bf;

    // load the whole row: element block jj covers columns 4*(lane + 64*jj)..+3
    float4 xv[16];
    #pragma unroll
    for (int jj = 0; jj < 16; ++jj) xv[jj] = xr[lane + 64 * jj];

    uint32_t* hist = &s_hist[w][0][0];
    uint32_t* m2p  = &s_m2[w * 8];

    // clear my histogram (each lane: 4 bins per copy) + survivor counter
    {
        uint4 z; z.x = z.y = z.z = z.w = 0u;
        *(uint4*)&hist[4 * lane]         = z;
        *(uint4*)&hist[HSTRW + 4 * lane] = z;
        if (lane == 0) *m2p = 0u;
    }
    wave_lgkm();

    // single histogram pass over candidates >= T0 with the composite digit
    // d = min((bits>>16) - 0x3F80, 255): monotone for all floats >= 1.0.
    const uint32_t cofs = (uint32_t)(lane & 1) * HSTRW;   // 2 copies within the wave
    const float T0f = 1.10f;   // performance heuristic only; exactness guarded below
    #pragma unroll
    for (int jj = 0; jj < 16; ++jj) {
        float4 b = bf4[lane + 64 * jj];
        float xb0 = xv[jj].x * b.x, xb1 = xv[jj].y * b.y;
        float xb2 = xv[jj].z * b.z, xb3 = xv[jj].w * b.w;
        if (xb0 >= T0f) { uint32_t d = (__float_as_uint(xb0) >> 16) - 0x3F80u; d = d > 255u ? 255u : d; atomicAdd(&hist[cofs + d], 1u); }
        if (xb1 >= T0f) { uint32_t d = (__float_as_uint(xb1) >> 16) - 0x3F80u; d = d > 255u ? 255u : d; atomicAdd(&hist[cofs + d], 1u); }
        if (xb2 >= T0f) { uint32_t d = (__float_as_uint(xb2) >> 16) - 0x3F80u; d = d > 255u ? 255u : d; atomicAdd(&hist[cofs + d], 1u); }
        if (xb3 >= T0f) { uint32_t d = (__float_as_uint(xb3) >> 16) - 0x3F80u; d = d > 255u ? 255u : d; atomicAdd(&hist[cofs + d], 1u); }
    }
    wave_lgkm();

    const uint32_t k = (uint32_t)kp[0];
    uint32_t rem = k;

    // per-wave copy-reduce + suffix-scan + digit pick (conflict-free uint4 reads)
    uint32_t dsel, packed;
    {
        uint4 a  = *(const uint4*)&hist[4 * lane];
        uint4 b2 = *(const uint4*)&hist[HSTRW + 4 * lane];
        uint32_t vv0 = a.x + b2.x, vv1 = a.y + b2.y, vv2 = a.z + b2.z, vv3 = a.w + b2.w;
        uint32_t s3 = vv3, s2 = vv2 + s3, s1 = vv1 + s2, s0 = vv0 + s1;
        uint32_t T = s0;
        #pragma unroll
        for (int off = 1; off < 64; off <<= 1) {
            uint32_t t = (uint32_t)__shfl_down((int)T, off, 64);
            if (lane + off < 64) T += t;
        }
        uint32_t Tex = T - s0;   // sum over lanes > lane
        uint32_t S0 = Tex + s0, S1 = Tex + s1, S2 = Tex + s2, S3 = Tex + s3;
        int b = -1; uint32_t sn = 0;
        if (S3 >= rem)      { b = 3; sn = S3 - vv3; }
        else if (S2 >= rem) { b = 2; sn = S2 - vv2; }
        else if (S1 >= rem) { b = 1; sn = S1 - vv1; }
        else if (S0 >= rem) { b = 0; sn = S0 - vv0; }
        packed = (b >= 0) ? ((((uint32_t)(4 * lane + b + 1)) << 16) | sn) : 0u;
        #pragma unroll
        for (int off = 1; off < 64; off <<= 1) {
            uint32_t o = (uint32_t)__shfl_xor((int)packed, off, 64);
            packed = packed > o ? packed : o;
        }
        dsel = (packed >> 16) - 1u;      // selected digit (if packed != 0)
        rem -= (packed & 0xFFFFu);       // rank within selected bin
    }

    float thr = 0.0f;
    bool need_fallback = (packed == 0u) || (dsel == 255u);

    if (!need_fallback) {
        const uint32_t hi16 = 0x3F80u + dsel;
        // scatter survivors (order irrelevant); may include a few elements in
        // [1.09375, T0) when dsel==0x0C — all strictly below every histogrammed
        // member, and rem <= member count, so the rem-th largest is unaffected.
        #pragma unroll
        for (int jj = 0; jj < 16; ++jj) {
            float4 b = bf4[lane + 64 * jj];
            float xb0 = xv[jj].x * b.x, xb1 = xv[jj].y * b.y;
            float xb2 = xv[jj].z * b.z, xb3 = xv[jj].w * b.w;
            uint32_t u0 = __float_as_uint(xb0), u1 = __float_as_uint(xb1);
            uint32_t u2 = __float_as_uint(xb2), u3 = __float_as_uint(xb3);
            if ((u0 >> 16) == hi16) { uint32_t p = atomicAdd(m2p, 1u); if (p < SURV_CAP) s_cand[w][p] = u0; }
            if ((u1 >> 16) == hi16) { uint32_t p = atomicAdd(m2p, 1u); if (p < SURV_CAP) s_cand[w][p] = u1; }
            if ((u2 >> 16) == hi16) { uint32_t p = atomicAdd(m2p, 1u); if (p < SURV_CAP) s_cand[w][p] = u2; }
            if ((u3 >> 16) == hi16) { uint32_t p = atomicAdd(m2p, 1u); if (p < SURV_CAP) s_cand[w][p] = u3; }
        }
        wave_lgkm();
        const uint32_t m2 = *m2p;
        if (m2 <= SURV_CAP) {
            // per-wave 16-bit ballot descent over this wave's survivors
            uint32_t cv = ((uint32_t)lane < m2) ? s_cand[w][lane] : ((~hi16) << 16);
            uint32_t cur = 0;
            #pragma unroll
            for (int bpos = 15; bpos >= 0; --bpos) {
                uint32_t t  = (hi16 << 16) | cur | (1u << bpos);
                uint32_t mk = ~((1u << bpos) - 1u);
                uint32_t c  = (uint32_t)__popcll(__ballot(((cv ^ t) & mk) == 0u));
                if (c >= rem) cur |= (1u << bpos);
                else          rem -= c;
            }
            thr = __uint_as_float((hi16 << 16) | cur);
        } else {
            need_fallback = true;
        }
    }

    if (need_fallback) {
        // exact 4-pass orderable radix over all 4096 elements (any input),
        // entirely wave-synchronous on this wave's private histogram
        {
            uint4 z; z.x = z.y = z.z = z.w = 0u;
            *(uint4*)&hist[4 * lane]         = z;
            *(uint4*)&hist[HSTRW + 4 * lane] = z;
        }
        wave_lgkm();
        uint32_t prefix = 0;
        rem = k;
        const uint32_t pmasks[4] = {0u, 0xFF000000u, 0xFFFF0000u, 0xFFFFFF00u};
        #pragma unroll 1
        for (int pass = 0; pass < 4; ++pass) {
            const int shift = 24 - pass * 8;
            const uint32_t pm = pmasks[pass];
            #pragma unroll
            for (int jj = 0; jj < 16; ++jj) {
                float4 b = bf4[lane + 64 * jj];
                float xb0 = xv[jj].x * b.x, xb1 = xv[jj].y * b.y;
                float xb2 = xv[jj].z * b.z, xb3 = xv[jj].w * b.w;
                uint32_t ou;
                ou = orderable(__float_as_uint(xb0));
                if (((ou ^ prefix) & pm) == 0u) atomicAdd(&hist[cofs + ((ou >> shift) & 255u)], 1u);
                ou = orderable(__float_as_uint(xb1));
                if (((ou ^ prefix) & pm) == 0u) atomicAdd(&hist[cofs + ((ou >> shift) & 255u)], 1u);
                ou = orderable(__float_as_uint(xb2));
                if (((ou ^ prefix) & pm) == 0u) atomicAdd(&hist[cofs + ((ou >> shift) & 255u)], 1u);
                ou = orderable(__float_as_uint(xb3));
                if (((ou ^ prefix) & pm) == 0u) atomicAdd(&hist[cofs + ((ou >> shift) & 255u)], 1u);
            }
            wave_lgkm();
            // read + zero my 4 bins per copy, then per-wave suffix-scan pick
            uint4 a  = *(const uint4*)&hist[4 * lane];
            uint4 b2 = *(const uint4*)&hist[HSTRW + 4 * lane];
            {
                uint4 z; z.x = z.y = z.z = z.w = 0u;
                *(uint4*)&hist[4 * lane]         = z;
                *(uint4*)&hist[HSTRW + 4 * lane] = z;
            }
            wave_lgkm();   // zeros land before next pass's atomics
            uint32_t vv0 = a.x + b2.x, vv1 = a.y + b2.y, vv2 = a.z + b2.z, vv3 = a.w + b2.w;
            uint32_t s3 = vv3, s2 = vv2 + s3, s1 = vv1 + s2, s0 = vv0 + s1;
            uint32_t T = s0;
            #pragma unroll
            for (int off = 1; off < 64; off <<= 1) {
                uint32_t t = (uint32_t)__shfl_down((int)T, off, 64);
                if (lane + off < 64) T += t;
            }
            uint32_t Tex = T - s0;
            uint32_t S0 = Tex + s0, S1 = Tex + s1, S2 = Tex + s2, S3 = Tex + s3;
            int b = -1; uint32_t sn = 0;
            if (S3 >= rem)      { b = 3; sn = S3 - vv3; }
            else if (S2 >= rem) { b = 2; sn = S2 - vv2; }
            else if (S1 >= rem) { b = 1; sn = S1 - vv1; }
            else if (S0 >= rem) { b = 0; sn = S0 - vv0; }
            uint32_t pk = (b >= 0) ? ((((uint32_t)(4 * lane + b + 1)) << 16) | sn) : 0u;
            #pragma unroll
            for (int off = 1; off < 64; off <<= 1) {
                uint32_t o = (uint32_t)__shfl_xor((int)pk, off, 64);
                pk = pk > o ? pk : o;
            }
            prefix |= ((pk >> 16) - 1u) << shift;
            rem -= (pk & 0xFFFFu);
        }
        // orderable-space -> float bits
        uint32_t tu = (prefix & 0x80000000u) ? (prefix & 0x7FFFFFFFu) : ~prefix;
        thr = __uint_as_float(tu);
    }

    // epilogue: recompute boosted (bit-identical mul), mask, store
    #pragma unroll
    for (int jj = 0; jj < 16; ++jj) {
        float4 b = bf4[lane + 64 * jj];
        float4 o;
        o.x = (xv[jj].x * b.x >= thr) ? xv[jj].x : 0.0f;
        o.y = (xv[jj].y * b.y >= thr) ? xv[jj].y : 0.0f;
        o.z = (xv[jj].z * b.z >= thr) ? xv[jj].z : 0.0f;
        o.w = (xv[jj].w * b.w >= thr) ? xv[jj].w : 0.0f;
        orow[lane + 64 * jj] = o;
    }
}

extern "C" void kernel_launch(void* const* d_in, const int* in_sizes, int n_in,
                              void* d_out, int out_size, void* d_ws, size_t ws_size,
                              hipStream_t stream) {
    const float* x  = (const float*)d_in[0];
    const float* dc = (const float*)d_in[1];
    const int*   kp = (const int*)d_in[2];
    float* out = (float*)d_out;
    float* bf  = (float*)d_ws;                 // 4096 floats of scratch

    const int n    = in_sizes[1];              // 4096
    const int rows = in_sizes[0] / n;          // 8192

    boost_kernel<<<(n + TPB - 1) / TPB, TPB, 0, stream>>>(dc, kp, bf);
    const int nb = (rows + WPB - 1) / WPB;     // 2048 blocks, 4 independent wave-rows each
    kwinner_kernel<<<nb, TPB, 0, stream>>>(x, bf, kp, out, rows);
}